// Round 18
// baseline (202.035 us; speedup 1.0000x reference)
//
#include <hip/hip_runtime.h>
#include <hip/hip_bf16.h>

typedef __attribute__((ext_vector_type(8))) __bf16 bf16x8;
typedef __attribute__((ext_vector_type(4))) float f32x4;

#define NN 100000
#define NE 1600000
#define NBK 6250          // 16-node buckets (NN/16 exactly)
#define NBG 1563          // 64-node groups (4 buckets per block), last partial
#define SUP 49            // supers of 2048 nodes (dst>>11), last partial
#define CAPA 36864        // super region capacity (mean 32768, +22 sigma)
#define EPB 2048          // edges per pass-A block
#define NBA 782           // ceil(NE/EPB)
#define NSLC 16           // slices per super in pass B
#define CAPB 384          // bucket cell capacity (mean 256, +8 sigma)
#define AST 136           // A-tile LDS stride in bf16 (272B: 16B-aligned rows, 2-way banks)

__device__ __forceinline__ float bflo(unsigned w) { return __uint_as_float(w << 16); }
__device__ __forceinline__ float bfhi(unsigned w) { return __uint_as_float(w & 0xffff0000u); }

// ---------------- K1: weights + x->bf16 + pass A (LDS-staged 49-way super binning) ---------
__global__ __launch_bounds__(512) void front_kernel(const float* __restrict__ W1,
                                                    const float* __restrict__ W2,
                                                    __bf16* __restrict__ W1T,
                                                    __bf16* __restrict__ W2T,
                                                    const float4* __restrict__ x4,
                                                    uint2* __restrict__ xb,
                                                    const int* __restrict__ esrc,
                                                    const int* __restrict__ edst,
                                                    const float* __restrict__ ev,
                                                    int* __restrict__ supercnt,
                                                    int2* __restrict__ psup) {
    __shared__ int scnt[SUP], sbase[SUP], scur[SUP];
    const int b = blockIdx.x, t = threadIdx.x;

    if (b < 64) {
        int tid = b * 512 + t;                         // 0..32767
        int k1 = tid >> 8, n1 = tid & 255;             // W1 is [128][256]
        W1T[n1 * 128 + k1] = (__bf16)W1[tid];
        int k2 = tid >> 7, n2 = tid & 127;             // W2 is [256][128]
        W2T[n2 * 256 + k2] = (__bf16)W2[tid];
    }
    for (int i = b * 512 + t; i < NN * 32; i += NBA * 512) {
        float4 v = x4[i];
        __bf16 b0 = (__bf16)v.x, b1 = (__bf16)v.y, b2 = (__bf16)v.z, b3 = (__bf16)v.w;
        uint2 o;
        o.x = (unsigned)*(unsigned short*)&b0 | ((unsigned)*(unsigned short*)&b1 << 16);
        o.y = (unsigned)*(unsigned short*)&b2 | ((unsigned)*(unsigned short*)&b3 << 16);
        xb[i] = o;
    }
    const int lo = b * EPB;
    const int hi = (lo + EPB < NE) ? lo + EPB : NE;
    if (t < SUP) scnt[t] = 0;
    __syncthreads();
    for (int e = lo + t; e < hi; e += 512)
        atomicAdd(&scnt[edst[e] >> 11], 1);
    __syncthreads();
    if (t < SUP) {
        int c = scnt[t];
        sbase[t] = c ? atomicAdd(&supercnt[t], c) : 0;
        scur[t] = 0;
    }
    __syncthreads();
    for (int e = lo + t; e < hi; e += 512) {
        int d = edst[e];
        int s = esrc[e];
        float v = ev[e];
        int sp = d >> 11;
        int off = sbase[sp] + atomicAdd(&scur[sp], 1);
        if (off < CAPA) {
            int2 p; p.x = (s << 11) | (d & 0x7FF); p.y = __float_as_int(v);
            psup[(size_t)sp * CAPA + off] = p;
        }
    }
}

// ---------------- K2: pass B — refine each super into its 128 16-node buckets ---------------
__global__ __launch_bounds__(512) void refine_kernel(const int2* __restrict__ psup,
                                                     const int* __restrict__ supercnt,
                                                     int* __restrict__ bktcnt,
                                                     int2* __restrict__ pairs2) {
    __shared__ int lcnt[128], lbase[128], lcur[128];
    const int s = blockIdx.x / NSLC, sl = blockIdx.x % NSLC, t = threadIdx.x;
    int cnt = supercnt[s]; if (cnt > CAPA) cnt = CAPA;
    const int per = (cnt + NSLC - 1) / NSLC;
    const int beg = sl * per;
    const int end = (beg + per < cnt) ? beg + per : cnt;
    const int2* seg = psup + (size_t)s * CAPA;

    if (t < 128) lcnt[t] = 0;
    __syncthreads();
    for (int i = beg + t; i < end; i += 512)
        atomicAdd(&lcnt[(seg[i].x >> 4) & 127], 1);
    __syncthreads();
    if (t < 128) {
        int c = lcnt[t];
        lbase[t] = c ? atomicAdd(&bktcnt[(s << 7) + t], c) : 0;
        lcur[t] = 0;
    }
    __syncthreads();
    for (int i = beg + t; i < end; i += 512) {
        int2 p = seg[i];
        int sub = (p.x >> 4) & 127;
        int off = lbase[sub] + atomicAdd(&lcur[sub], 1);
        if (off < CAPB)
            pairs2[(size_t)((s << 7) + sub) * CAPB + off] = p;
    }
}

// ---------------- K3: fused sort + gather + 2-layer MFMA MLP, one block per 64-node group ---
// 1024 threads = 16 waves; 4 cells (16-node buckets) processed sequentially; per cell,
// wave w gathers node bk*16+w (r17's proven inner loop) and writes its bf16 A-tile row to
// LDS; then stage1/stage2 MFMA (the proven mlp body) runs on the 64x128 tile in-block.
// LDS overlay: At [64][AST] persistent; region X = raw/srt (sort) then Hl (MLP).
__global__ __launch_bounds__(1024) void gather_mlp_kernel(const unsigned* __restrict__ xb,
                                                          const int* __restrict__ bktcnt,
                                                          const int2* __restrict__ pairs2,
                                                          const float* __restrict__ eps,
                                                          const __bf16* __restrict__ W1T,
                                                          const __bf16* __restrict__ W2T,
                                                          const float* __restrict__ b1,
                                                          const float* __restrict__ b2,
                                                          float* __restrict__ out) {
    __shared__ __attribute__((aligned(16))) char smem[17408 + 33792];
    __bf16* At  = (__bf16*)smem;                      // [64][AST]  17408 B, persistent
    char*   X   = smem + 17408;
    int2*   raw = (int2*)X;                           // [CAPB] 3072 B  (sort phase)
    int2*   srt = (int2*)(X + 3072);                  // [CAPB] 3072 B  (sort phase)
    __bf16* Hl  = (__bf16*)X;                         // [64][264] 33792 B (MLP phase)
    __shared__ int rcnt[16], rofs[16], rcur[16];

    const int t = threadIdx.x;
    const int B = blockIdx.x;
    const int wave = t >> 6, lane = t & 63;
    const unsigned hw = lane >> 5, l32 = lane & 31u;
    const char* xbase = (const char*)xb + l32 * 8;
    const float sc = 1.0f + eps[0];

    for (int c = 0; c < 4; ++c) {
        const int bk = B * 4 + c;
        int m = (bk < NBK) ? bktcnt[bk] : 0;
        if (m > CAPB) m = CAPB;
        const int2* seg = pairs2 + (size_t)bk * CAPB;

        __syncthreads();                               // protect srt/rcnt from prev cell
        if (t < 16) rcnt[t] = 0;
        __syncthreads();
        for (int i = t; i < m; i += 1024) {
            int2 p = seg[i];
            raw[i] = p;
            atomicAdd(&rcnt[p.x & 15], 1);
        }
        __syncthreads();
        if (t == 0) {
            int run = 0;
#pragma unroll
            for (int r = 0; r < 16; ++r) { rofs[r] = run; rcur[r] = run; run += rcnt[r]; }
        }
        __syncthreads();
        for (int i = t; i < m; i += 1024) {
            int2 p = raw[i];
            int pos = atomicAdd(&rcur[p.x & 15], 1);
            int2 q; q.x = (p.x >> 3) & 0xFFFFFF00;     // src byte offset (src*256)
            q.y = p.y;
            srt[pos] = q;
        }
        __syncthreads();

        // gather: wave w owns node bk*16+w; half-waves interleave, 4 edges/half in flight
        float a0 = 0.f, a1 = 0.f, a2 = 0.f, a3 = 0.f;
        {
            const int je = rofs[wave] + rcnt[wave];
            int j = rofs[wave] + (int)hw;
            for (; j + 6 < je; j += 8) {
                int2 e0 = srt[j], e1 = srt[j + 2], e2 = srt[j + 4], e3 = srt[j + 6];
                uint2 w0 = *(const uint2*)(xbase + e0.x);
                uint2 w1 = *(const uint2*)(xbase + e1.x);
                uint2 w2 = *(const uint2*)(xbase + e2.x);
                uint2 w3 = *(const uint2*)(xbase + e3.x);
                float v0 = __int_as_float(e0.y), v1 = __int_as_float(e1.y);
                float v2 = __int_as_float(e2.y), v3 = __int_as_float(e3.y);
                a0 = fmaf(v0, bflo(w0.x), a0); a1 = fmaf(v0, bfhi(w0.x), a1);
                a2 = fmaf(v0, bflo(w0.y), a2); a3 = fmaf(v0, bfhi(w0.y), a3);
                a0 = fmaf(v1, bflo(w1.x), a0); a1 = fmaf(v1, bfhi(w1.x), a1);
                a2 = fmaf(v1, bflo(w1.y), a2); a3 = fmaf(v1, bfhi(w1.y), a3);
                a0 = fmaf(v2, bflo(w2.x), a0); a1 = fmaf(v2, bfhi(w2.x), a1);
                a2 = fmaf(v2, bflo(w2.y), a2); a3 = fmaf(v2, bfhi(w2.y), a3);
                a0 = fmaf(v3, bflo(w3.x), a0); a1 = fmaf(v3, bfhi(w3.x), a1);
                a2 = fmaf(v3, bflo(w3.y), a2); a3 = fmaf(v3, bfhi(w3.y), a3);
            }
            for (; j < je; j += 2) {
                int2 e0 = srt[j];
                uint2 w0 = *(const uint2*)(xbase + e0.x);
                float v0 = __int_as_float(e0.y);
                a0 = fmaf(v0, bflo(w0.x), a0); a1 = fmaf(v0, bfhi(w0.x), a1);
                a2 = fmaf(v0, bflo(w0.y), a2); a3 = fmaf(v0, bfhi(w0.y), a3);
            }
        }
        a0 += __shfl_xor(a0, 32); a1 += __shfl_xor(a1, 32);
        a2 += __shfl_xor(a2, 32); a3 += __shfl_xor(a3, 32);
        if (hw == 0) {
            const int n = bk * 16 + wave;
            unsigned p0 = 0, p1 = 0;
            if (n < NN) {
                uint2 ws = *(const uint2*)(xbase + (size_t)n * 256);
                a0 = fmaf(sc, bflo(ws.x), a0); a1 = fmaf(sc, bfhi(ws.x), a1);
                a2 = fmaf(sc, bflo(ws.y), a2); a3 = fmaf(sc, bfhi(ws.y), a3);
                __bf16 c0 = (__bf16)a0, c1 = (__bf16)a1, c2 = (__bf16)a2, c3 = (__bf16)a3;
                p0 = (unsigned)*(unsigned short*)&c0 | ((unsigned)*(unsigned short*)&c1 << 16);
                p1 = (unsigned)*(unsigned short*)&c2 | ((unsigned)*(unsigned short*)&c3 << 16);
            }
            const int r = c * 16 + wave;               // A-tile row
            uint2 o; o.x = p0; o.y = p1;
            *(uint2*)((char*)At + (size_t)r * (AST * 2) + l32 * 8) = o;
        }
    }
    __syncthreads();                                   // A-tile complete; srt dead

    const int l15 = lane & 15, lhi = lane >> 4;

    // ---- stage 1: Hl = relu(At @ W1 + b1); wave owns 16 of 256 H-cols ----
    {
        f32x4 acc1[4] = {};
        const int n = wave * 16 + l15;
        const __bf16* w1p = W1T + (size_t)n * 128;
#pragma unroll
        for (int ks = 0; ks < 4; ++ks) {
            const int k0 = ks * 32 + lhi * 8;
            bf16x8 bn = *(const bf16x8*)(w1p + k0);
#pragma unroll
            for (int mt = 0; mt < 4; ++mt) {
                bf16x8 am = *(const bf16x8*)(At + (size_t)(mt * 16 + l15) * AST + k0);
                acc1[mt] = __builtin_amdgcn_mfma_f32_16x16x32_bf16(am, bn, acc1[mt], 0, 0, 0);
            }
        }
        float bias = b1[n];
#pragma unroll
        for (int mt = 0; mt < 4; ++mt)
#pragma unroll
            for (int r = 0; r < 4; ++r) {
                float h = acc1[mt][r] + bias;
                Hl[(size_t)(mt * 16 + lhi * 4 + r) * 264 + n] = (__bf16)fmaxf(h, 0.0f);
            }
    }
    __syncthreads();

    // ---- stage 2: out = Hl @ W2 + b2; wave owns 2 of 32 (mt,nt) 16x16 tiles ----
    {
        f32x4 acc2[2] = {};
#pragma unroll
        for (int ks = 0; ks < 8; ++ks) {
            const int k0 = ks * 32 + lhi * 8;
#pragma unroll
            for (int a = 0; a < 2; ++a) {
                const int idx = wave * 2 + a;
                const int mt = idx >> 3, nt = idx & 7;
                bf16x8 ha = *(const bf16x8*)(Hl + (size_t)(mt * 16 + l15) * 264 + k0);
                bf16x8 wb = *(const bf16x8*)(W2T + (size_t)(nt * 16 + l15) * 256 + k0);
                acc2[a] = __builtin_amdgcn_mfma_f32_16x16x32_bf16(ha, wb, acc2[a], 0, 0, 0);
            }
        }
#pragma unroll
        for (int a = 0; a < 2; ++a) {
            const int idx = wave * 2 + a;
            const int mt = idx >> 3, nt = idx & 7;
            const int col = nt * 16 + l15;
            float bias = b2[col];
#pragma unroll
            for (int r = 0; r < 4; ++r) {
                int row = B * 64 + mt * 16 + lhi * 4 + r;
                if (row < NN) out[(size_t)row * 128 + col] = acc2[a][r] + bias;
            }
        }
    }
}

// ---------------- fallback path ----------------
__global__ void convert_w_kernel(const float* __restrict__ W1, const float* __restrict__ W2,
                                 __bf16* __restrict__ W1T, __bf16* __restrict__ W2T) {
    int tid = blockIdx.x * 256 + threadIdx.x;
    if (tid < 128 * 256) {
        int k1 = tid >> 8, n1 = tid & 255;
        W1T[n1 * 128 + k1] = (__bf16)W1[tid];
        int k2 = tid >> 7, n2 = tid & 127;
        W2T[n2 * 256 + k2] = (__bf16)W2[tid];
    }
}

__global__ void init_ax_kernel(const float4* __restrict__ x, float4* __restrict__ AX,
                               const float* __restrict__ eps, int n4) {
    int i = blockIdx.x * blockDim.x + threadIdx.x;
    if (i >= n4) return;
    float s = 1.0f + eps[0];
    float4 v = x[i];
    v.x *= s; v.y *= s; v.z *= s; v.w *= s;
    AX[i] = v;
}

__global__ void scatter_kernel(const float2* __restrict__ x2, const float* __restrict__ ev,
                               const int* __restrict__ esrc, const int* __restrict__ edst,
                               float* AX) {
    unsigned gid = blockIdx.x * 256u + threadIdx.x;
    unsigned e = gid >> 6;
    unsigned lane = gid & 63u;
    if (e >= NE) return;
    float v = ev[e];
    int s = esrc[e], d = edst[e];
    float2 xv = x2[(size_t)s * 64 + lane];
    float* dstp = AX + (size_t)d * 128 + lane * 2;
    atomicAdd(dstp,     v * xv.x);
    atomicAdd(dstp + 1, v * xv.y);
}

__global__ __launch_bounds__(256) void mlp_kernel(const float* A,
                                                  const __bf16* __restrict__ W1T,
                                                  const __bf16* __restrict__ W2T,
                                                  const float* __restrict__ b1,
                                                  const float* __restrict__ b2,
                                                  float* out) {
    __shared__ __bf16 Hl[64][264];
    const int wave = threadIdx.x >> 6;
    const int lane = threadIdx.x & 63;
    const int l15  = lane & 15;
    const int lhi  = lane >> 4;
    const int rowbase = blockIdx.x * 64;

    f32x4 acc1[4][4] = {};
#pragma unroll
    for (int ks = 0; ks < 4; ++ks) {
        const int k0 = ks * 32 + lhi * 8;
        bf16x8 am[4], bn[4];
#pragma unroll
        for (int mt = 0; mt < 4; ++mt) {
            int row = rowbase + mt * 16 + l15;
            if (row >= NN) row = NN - 1;
            const float4* ap = (const float4*)(A + (size_t)row * 128 + k0);
            float4 f0 = ap[0], f1 = ap[1];
            bf16x8 a;
            a[0]=(__bf16)f0.x; a[1]=(__bf16)f0.y; a[2]=(__bf16)f0.z; a[3]=(__bf16)f0.w;
            a[4]=(__bf16)f1.x; a[5]=(__bf16)f1.y; a[6]=(__bf16)f1.z; a[7]=(__bf16)f1.w;
            am[mt] = a;
        }
#pragma unroll
        for (int nt = 0; nt < 4; ++nt) {
            int n = wave * 64 + nt * 16 + l15;
            bn[nt] = *(const bf16x8*)(W1T + (size_t)n * 128 + k0);
        }
#pragma unroll
        for (int mt = 0; mt < 4; ++mt)
#pragma unroll
            for (int nt = 0; nt < 4; ++nt)
                acc1[mt][nt] = __builtin_amdgcn_mfma_f32_16x16x32_bf16(am[mt], bn[nt], acc1[mt][nt], 0, 0, 0);
    }
#pragma unroll
    for (int nt = 0; nt < 4; ++nt) {
        int n = wave * 64 + nt * 16 + l15;
        float bias = b1[n];
#pragma unroll
        for (int mt = 0; mt < 4; ++mt)
#pragma unroll
            for (int r = 0; r < 4; ++r) {
                float h = acc1[mt][nt][r] + bias;
                Hl[mt * 16 + lhi * 4 + r][n] = (__bf16)fmaxf(h, 0.0f);
            }
    }
    __syncthreads();

    f32x4 acc2[4][2] = {};
#pragma unroll
    for (int ks = 0; ks < 8; ++ks) {
        const int k0 = ks * 32 + lhi * 8;
        bf16x8 ha[4], wb[2];
#pragma unroll
        for (int mt = 0; mt < 4; ++mt)
            ha[mt] = *(const bf16x8*)(&Hl[mt * 16 + l15][k0]);
#pragma unroll
        for (int nt = 0; nt < 2; ++nt) {
            int n = wave * 32 + nt * 16 + l15;
            wb[nt] = *(const bf16x8*)(W2T + (size_t)n * 256 + k0);
        }
#pragma unroll
        for (int mt = 0; mt < 4; ++mt)
#pragma unroll
            for (int nt = 0; nt < 2; ++nt)
                acc2[mt][nt] = __builtin_amdgcn_mfma_f32_16x16x32_bf16(ha[mt], wb[nt], acc2[mt][nt], 0, 0, 0);
    }
#pragma unroll
    for (int nt = 0; nt < 2; ++nt) {
        int n = wave * 32 + nt * 16 + l15;
        float bias = b2[n];
#pragma unroll
        for (int mt = 0; mt < 4; ++mt)
#pragma unroll
            for (int r = 0; r < 4; ++r) {
                int row = rowbase + mt * 16 + lhi * 4 + r;
                if (row < NN) out[(size_t)row * 128 + n] = acc2[mt][nt][r] + bias;
            }
    }
}

extern "C" void kernel_launch(void* const* d_in, const int* in_sizes, int n_in,
                              void* d_out, int out_size, void* d_ws, size_t ws_size,
                              hipStream_t stream) {
    const float* x    = (const float*)d_in[0];
    const float* ev   = (const float*)d_in[1];
    const float* W1   = (const float*)d_in[2];
    const float* b1   = (const float*)d_in[3];
    const float* W2   = (const float*)d_in[4];
    const float* b2   = (const float*)d_in[5];
    const float* eps  = (const float*)d_in[6];
    const int*   esrc = (const int*)d_in[7];
    const int*   edst = (const int*)d_in[8];
    float* out = (float*)d_out;

    char* ws = (char*)d_ws;
    size_t off = 0;
    auto alloc = [&](size_t bytes) { void* p = ws + off; off += (bytes + 511) & ~size_t(511); return p; };

    __bf16* W1T   = (__bf16*)alloc(128 * 256 * sizeof(__bf16));
    __bf16* W2T   = (__bf16*)alloc(128 * 256 * sizeof(__bf16));
    int* cnts     = (int*)  alloc((size_t)(SUP + NBK) * sizeof(int));       // supercnt | bktcnt
    int2* psup    = (int2*) alloc((size_t)SUP * CAPA * sizeof(int2));       // 14.5 MB
    int2* pairs2  = (int2*) alloc((size_t)NBK * CAPB * sizeof(int2));       // 19.2 MB
    unsigned* xb  = (unsigned*)alloc((size_t)NN * 64 * sizeof(unsigned));   // bf16 x
    bool csr_ok = (off <= ws_size);

    if (csr_ok) {
        int* supercnt = cnts;
        int* bktcnt   = cnts + SUP;
        hipMemsetAsync(cnts, 0, (size_t)(SUP + NBK) * sizeof(int), stream);
        front_kernel<<<NBA, 512, 0, stream>>>(W1, W2, W1T, W2T, (const float4*)x,
                                              (uint2*)xb, esrc, edst, ev, supercnt, psup);
        refine_kernel<<<SUP * NSLC, 512, 0, stream>>>(psup, supercnt, bktcnt, pairs2);
        gather_mlp_kernel<<<NBG, 1024, 0, stream>>>(xb, bktcnt, pairs2, eps,
                                                    W1T, W2T, b1, b2, out);
    } else {
        // fallback: atomic scatter path (fp32 AX in d_out)
        __bf16* W1Tf = (__bf16*)ws;
        __bf16* W2Tf = W1Tf + 128 * 256;
        convert_w_kernel<<<128, 256, 0, stream>>>(W1, W2, W1Tf, W2Tf);
        int n4 = NN * 128 / 4;
        init_ax_kernel<<<(n4 + 255) / 256, 256, 0, stream>>>((const float4*)x, (float4*)out, eps, n4);
        scatter_kernel<<<(NE * 64u) / 256u, 256, 0, stream>>>((const float2*)x, ev, esrc, edst, out);
        int nblk = (NN + 63) / 64;
        mlp_kernel<<<nblk, 256, 0, stream>>>(out, W1Tf, W2Tf, b1, b2, out);
    }
}

// Round 19
// 170.246 us; speedup vs baseline: 1.1867x; 1.1867x over previous
//
#include <hip/hip_runtime.h>
#include <hip/hip_bf16.h>

typedef __attribute__((ext_vector_type(8))) __bf16 bf16x8;
typedef __attribute__((ext_vector_type(4))) float f32x4;

#define NN 100000
#define NE 1600000
#define NBK 6250          // 16-node buckets (NN/16 exactly)
#define SUP 49            // supers of 2048 nodes (dst>>11), last partial
#define CAPA 36864        // super region capacity (mean 32768, +22 sigma)
#define EPB 2048          // edges per pass-A block
#define NBA 782           // ceil(NE/EPB)
#define NSLC 16           // slices per super in pass B
#define CAPB 384          // bucket cell capacity (mean 256, +8 sigma)

__device__ __forceinline__ float bflo(unsigned w) { return __uint_as_float(w << 16); }
__device__ __forceinline__ float bfhi(unsigned w) { return __uint_as_float(w & 0xffff0000u); }

// ---------------- K1: weights + x->bf16 + pass A (LDS-staged 49-way super binning) ---------
// Per-wave hist + per-wave append cursors: 8 private counter sets -> ~8x less LDS-atomic
// same-address serialization than a single shared set.
__global__ __launch_bounds__(512) void front_kernel(const float* __restrict__ W1,
                                                    const float* __restrict__ W2,
                                                    __bf16* __restrict__ W1T,
                                                    __bf16* __restrict__ W2T,
                                                    const float4* __restrict__ x4,
                                                    uint2* __restrict__ xb,
                                                    const int* __restrict__ esrc,
                                                    const int* __restrict__ edst,
                                                    const float* __restrict__ ev,
                                                    int* __restrict__ supercnt,
                                                    int2* __restrict__ psup) {
    __shared__ int scnt[8][SUP];   // per-wave counts
    __shared__ int wcur[8][SUP];   // per-wave absolute write cursors
    const int b = blockIdx.x, t = threadIdx.x;
    const int wave = t >> 6;

    if (b < 64) {
        int tid = b * 512 + t;                         // 0..32767
        int k1 = tid >> 8, n1 = tid & 255;             // W1 is [128][256]
        W1T[n1 * 128 + k1] = (__bf16)W1[tid];
        int k2 = tid >> 7, n2 = tid & 127;             // W2 is [256][128]
        W2T[n2 * 256 + k2] = (__bf16)W2[tid];
    }
    for (int i = b * 512 + t; i < NN * 32; i += NBA * 512) {
        float4 v = x4[i];
        __bf16 b0 = (__bf16)v.x, b1 = (__bf16)v.y, b2 = (__bf16)v.z, b3 = (__bf16)v.w;
        uint2 o;
        o.x = (unsigned)*(unsigned short*)&b0 | ((unsigned)*(unsigned short*)&b1 << 16);
        o.y = (unsigned)*(unsigned short*)&b2 | ((unsigned)*(unsigned short*)&b3 << 16);
        xb[i] = o;
    }
    // pass A over this block's contiguous edge slice
    const int lo = b * EPB;
    const int hi = (lo + EPB < NE) ? lo + EPB : NE;
    for (int i = t; i < 8 * SUP; i += 512) ((int*)scnt)[i] = 0;
    __syncthreads();
    for (int e = lo + t; e < hi; e += 512)
        atomicAdd(&scnt[wave][edst[e] >> 11], 1);
    __syncthreads();
    if (t < SUP) {
        int tot = 0;
#pragma unroll
        for (int w = 0; w < 8; ++w) tot += scnt[w][t];
        int run = tot ? atomicAdd(&supercnt[t], tot) : 0;
#pragma unroll
        for (int w = 0; w < 8; ++w) { wcur[w][t] = run; run += scnt[w][t]; }
    }
    __syncthreads();
    for (int e = lo + t; e < hi; e += 512) {
        int d = edst[e];
        int s = esrc[e];
        float v = ev[e];
        int sp = d >> 11;
        int off = atomicAdd(&wcur[wave][sp], 1);
        if (off < CAPA) {
            int2 p; p.x = (s << 11) | (d & 0x7FF); p.y = __float_as_int(v);
            psup[(size_t)sp * CAPA + off] = p;
        }
    }
}

// ---------------- K2: pass B — refine each super into its 128 16-node buckets ---------------
__global__ __launch_bounds__(512) void refine_kernel(const int2* __restrict__ psup,
                                                     const int* __restrict__ supercnt,
                                                     int* __restrict__ bktcnt,
                                                     int2* __restrict__ pairs2) {
    __shared__ int lcnt[128], lbase[128], lcur[128];
    const int s = blockIdx.x / NSLC, sl = blockIdx.x % NSLC, t = threadIdx.x;
    int cnt = supercnt[s]; if (cnt > CAPA) cnt = CAPA;
    const int per = (cnt + NSLC - 1) / NSLC;
    const int beg = sl * per;
    const int end = (beg + per < cnt) ? beg + per : cnt;
    const int2* seg = psup + (size_t)s * CAPA;

    if (t < 128) lcnt[t] = 0;
    __syncthreads();
    for (int i = beg + t; i < end; i += 512)
        atomicAdd(&lcnt[(seg[i].x >> 4) & 127], 1);
    __syncthreads();
    if (t < 128) {
        int c = lcnt[t];
        lbase[t] = c ? atomicAdd(&bktcnt[(s << 7) + t], c) : 0;
        lcur[t] = 0;
    }
    __syncthreads();
    for (int i = beg + t; i < end; i += 512) {
        int2 p = seg[i];
        int sub = (p.x >> 4) & 127;
        int off = lbase[sub] + atomicAdd(&lcur[sub], 1);
        if (off < CAPB)
            pairs2[(size_t)((s << 7) + sub) * CAPB + off] = p;
    }
}

// ---------------- K3: fused LDS-sort + gather, one block per 16-node bucket -----------------
// 512 threads = 8 waves; wave w gathers nodes b*16 + 2w and 2w+1 sequentially.
// 4 blocks/CU (vs 2 at 1024 threads) -> one block's sort barriers hide under another's loads.
__global__ __launch_bounds__(512) void sort_gather_kernel(const unsigned* __restrict__ xb,
                                                          const int* __restrict__ bktcnt,
                                                          const int2* __restrict__ pairs2,
                                                          const float* __restrict__ eps,
                                                          uint2* __restrict__ AXb) {
    __shared__ int2 raw[CAPB];
    __shared__ int2 srt[CAPB];
    __shared__ int rcnt[16], rofs[16], rcur[16];

    const int t = threadIdx.x;
    const int b = blockIdx.x;
    const int wave = t >> 6, lane = t & 63;
    const unsigned hw = lane >> 5, l32 = lane & 31u;
    const char* xbase = (const char*)xb + l32 * 8;

    int m = bktcnt[b]; if (m > CAPB) m = CAPB;
    const int2* seg = pairs2 + (size_t)b * CAPB;

    if (t < 16) rcnt[t] = 0;
    __syncthreads();
    for (int i = t; i < m; i += 512) {
        int2 p = seg[i];
        raw[i] = p;
        atomicAdd(&rcnt[p.x & 15], 1);
    }
    __syncthreads();
    if (t == 0) {
        int run = 0;
#pragma unroll
        for (int r = 0; r < 16; ++r) { rofs[r] = run; rcur[r] = run; run += rcnt[r]; }
    }
    __syncthreads();
    for (int i = t; i < m; i += 512) {
        int2 p = raw[i];
        int pos = atomicAdd(&rcur[p.x & 15], 1);
        int2 q; q.x = (p.x >> 3) & 0xFFFFFF00;         // src byte offset (src*256)
        q.y = p.y;
        srt[pos] = q;
    }
    __syncthreads();

    // gather: wave w owns nodes 2w and 2w+1; half-waves interleave, 4 edges/half in flight
#pragma unroll
    for (int sub = 0; sub < 2; ++sub) {
        const int r = wave * 2 + sub;
        float a0 = 0.f, a1 = 0.f, a2 = 0.f, a3 = 0.f;
        const int je = rofs[r] + rcnt[r];
        int j = rofs[r] + (int)hw;
        for (; j + 6 < je; j += 8) {
            int2 e0 = srt[j], e1 = srt[j + 2], e2 = srt[j + 4], e3 = srt[j + 6];
            uint2 w0 = *(const uint2*)(xbase + e0.x);
            uint2 w1 = *(const uint2*)(xbase + e1.x);
            uint2 w2 = *(const uint2*)(xbase + e2.x);
            uint2 w3 = *(const uint2*)(xbase + e3.x);
            float v0 = __int_as_float(e0.y), v1 = __int_as_float(e1.y);
            float v2 = __int_as_float(e2.y), v3 = __int_as_float(e3.y);
            a0 = fmaf(v0, bflo(w0.x), a0); a1 = fmaf(v0, bfhi(w0.x), a1);
            a2 = fmaf(v0, bflo(w0.y), a2); a3 = fmaf(v0, bfhi(w0.y), a3);
            a0 = fmaf(v1, bflo(w1.x), a0); a1 = fmaf(v1, bfhi(w1.x), a1);
            a2 = fmaf(v1, bflo(w1.y), a2); a3 = fmaf(v1, bfhi(w1.y), a3);
            a0 = fmaf(v2, bflo(w2.x), a0); a1 = fmaf(v2, bfhi(w2.x), a1);
            a2 = fmaf(v2, bflo(w2.y), a2); a3 = fmaf(v2, bfhi(w2.y), a3);
            a0 = fmaf(v3, bflo(w3.x), a0); a1 = fmaf(v3, bfhi(w3.x), a1);
            a2 = fmaf(v3, bflo(w3.y), a2); a3 = fmaf(v3, bfhi(w3.y), a3);
        }
        for (; j < je; j += 2) {
            int2 e0 = srt[j];
            uint2 w0 = *(const uint2*)(xbase + e0.x);
            float v0 = __int_as_float(e0.y);
            a0 = fmaf(v0, bflo(w0.x), a0); a1 = fmaf(v0, bfhi(w0.x), a1);
            a2 = fmaf(v0, bflo(w0.y), a2); a3 = fmaf(v0, bfhi(w0.y), a3);
        }

        a0 += __shfl_xor(a0, 32); a1 += __shfl_xor(a1, 32);
        a2 += __shfl_xor(a2, 32); a3 += __shfl_xor(a3, 32);
        if (hw == 0) {
            const int n = b * 16 + r;                  // NN = 6250*16 exactly
            uint2 ws = *(const uint2*)(xbase + (size_t)n * 256);
            float sc = 1.0f + eps[0];
            a0 = fmaf(sc, bflo(ws.x), a0); a1 = fmaf(sc, bfhi(ws.x), a1);
            a2 = fmaf(sc, bflo(ws.y), a2); a3 = fmaf(sc, bfhi(ws.y), a3);
            __bf16 b0 = (__bf16)a0, b1 = (__bf16)a1, b2 = (__bf16)a2, b3 = (__bf16)a3;
            uint2 o;
            o.x = (unsigned)*(unsigned short*)&b0 | ((unsigned)*(unsigned short*)&b1 << 16);
            o.y = (unsigned)*(unsigned short*)&b2 | ((unsigned)*(unsigned short*)&b3 << 16);
            AXb[(size_t)n * 32 + l32] = o;
        }
    }
}

// ---------------- fallback path ----------------
__global__ void convert_w_kernel(const float* __restrict__ W1, const float* __restrict__ W2,
                                 __bf16* __restrict__ W1T, __bf16* __restrict__ W2T) {
    int tid = blockIdx.x * 256 + threadIdx.x;
    if (tid < 128 * 256) {
        int k1 = tid >> 8, n1 = tid & 255;
        W1T[n1 * 128 + k1] = (__bf16)W1[tid];
        int k2 = tid >> 7, n2 = tid & 127;
        W2T[n2 * 256 + k2] = (__bf16)W2[tid];
    }
}

__global__ void init_ax_kernel(const float4* __restrict__ x, float4* __restrict__ AX,
                               const float* __restrict__ eps, int n4) {
    int i = blockIdx.x * blockDim.x + threadIdx.x;
    if (i >= n4) return;
    float s = 1.0f + eps[0];
    float4 v = x[i];
    v.x *= s; v.y *= s; v.z *= s; v.w *= s;
    AX[i] = v;
}

__global__ void scatter_kernel(const float2* __restrict__ x2, const float* __restrict__ ev,
                               const int* __restrict__ esrc, const int* __restrict__ edst,
                               float* AX) {
    unsigned gid = blockIdx.x * 256u + threadIdx.x;
    unsigned e = gid >> 6;
    unsigned lane = gid & 63u;
    if (e >= NE) return;
    float v = ev[e];
    int s = esrc[e], d = edst[e];
    float2 xv = x2[(size_t)s * 64 + lane];
    float* dstp = AX + (size_t)d * 128 + lane * 2;
    atomicAdd(dstp,     v * xv.x);
    atomicAdd(dstp + 1, v * xv.y);
}

// ---------------- K4: fused 2-layer MLP: out = relu(A@W1+b1)@W2+b2 ----------------
template <typename AT>
__global__ __launch_bounds__(256) void mlp_kernel(const AT* A,
                                                  const __bf16* __restrict__ W1T,
                                                  const __bf16* __restrict__ W2T,
                                                  const float* __restrict__ b1,
                                                  const float* __restrict__ b2,
                                                  float* out) {
    __shared__ __bf16 Hl[64][264];

    const int wave = threadIdx.x >> 6;
    const int lane = threadIdx.x & 63;
    const int l15  = lane & 15;
    const int lhi  = lane >> 4;
    const int rowbase = blockIdx.x * 64;

    f32x4 acc1[4][4] = {};
#pragma unroll
    for (int ks = 0; ks < 4; ++ks) {
        const int k0 = ks * 32 + lhi * 8;
        bf16x8 am[4], bn[4];
#pragma unroll
        for (int mt = 0; mt < 4; ++mt) {
            int row = rowbase + mt * 16 + l15;
            if (row >= NN) row = NN - 1;
            if constexpr (__is_same(AT, __bf16)) {
                am[mt] = *(const bf16x8*)(A + (size_t)row * 128 + k0);
            } else {
                const float4* ap = (const float4*)(A + (size_t)row * 128 + k0);
                float4 f0 = ap[0], f1 = ap[1];
                bf16x8 a;
                a[0]=(__bf16)f0.x; a[1]=(__bf16)f0.y; a[2]=(__bf16)f0.z; a[3]=(__bf16)f0.w;
                a[4]=(__bf16)f1.x; a[5]=(__bf16)f1.y; a[6]=(__bf16)f1.z; a[7]=(__bf16)f1.w;
                am[mt] = a;
            }
        }
#pragma unroll
        for (int nt = 0; nt < 4; ++nt) {
            int n = wave * 64 + nt * 16 + l15;
            bn[nt] = *(const bf16x8*)(W1T + (size_t)n * 128 + k0);
        }
#pragma unroll
        for (int mt = 0; mt < 4; ++mt)
#pragma unroll
            for (int nt = 0; nt < 4; ++nt)
                acc1[mt][nt] = __builtin_amdgcn_mfma_f32_16x16x32_bf16(am[mt], bn[nt], acc1[mt][nt], 0, 0, 0);
    }

#pragma unroll
    for (int nt = 0; nt < 4; ++nt) {
        int n = wave * 64 + nt * 16 + l15;
        float bias = b1[n];
#pragma unroll
        for (int mt = 0; mt < 4; ++mt)
#pragma unroll
            for (int r = 0; r < 4; ++r) {
                float h = acc1[mt][nt][r] + bias;
                Hl[mt * 16 + lhi * 4 + r][n] = (__bf16)fmaxf(h, 0.0f);
            }
    }
    __syncthreads();

    f32x4 acc2[4][2] = {};
#pragma unroll
    for (int ks = 0; ks < 8; ++ks) {
        const int k0 = ks * 32 + lhi * 8;
        bf16x8 ha[4], wb[2];
#pragma unroll
        for (int mt = 0; mt < 4; ++mt)
            ha[mt] = *(const bf16x8*)(&Hl[mt * 16 + l15][k0]);
#pragma unroll
        for (int nt = 0; nt < 2; ++nt) {
            int n = wave * 32 + nt * 16 + l15;
            wb[nt] = *(const bf16x8*)(W2T + (size_t)n * 256 + k0);
        }
#pragma unroll
        for (int mt = 0; mt < 4; ++mt)
#pragma unroll
            for (int nt = 0; nt < 2; ++nt)
                acc2[mt][nt] = __builtin_amdgcn_mfma_f32_16x16x32_bf16(ha[mt], wb[nt], acc2[mt][nt], 0, 0, 0);
    }

#pragma unroll
    for (int nt = 0; nt < 2; ++nt) {
        int n = wave * 32 + nt * 16 + l15;
        float bias = b2[n];
#pragma unroll
        for (int mt = 0; mt < 4; ++mt)
#pragma unroll
            for (int r = 0; r < 4; ++r) {
                int row = rowbase + mt * 16 + lhi * 4 + r;
                if (row < NN) out[(size_t)row * 128 + n] = acc2[mt][nt][r] + bias;
            }
    }
}

extern "C" void kernel_launch(void* const* d_in, const int* in_sizes, int n_in,
                              void* d_out, int out_size, void* d_ws, size_t ws_size,
                              hipStream_t stream) {
    const float* x    = (const float*)d_in[0];
    const float* ev   = (const float*)d_in[1];
    const float* W1   = (const float*)d_in[2];
    const float* b1   = (const float*)d_in[3];
    const float* W2   = (const float*)d_in[4];
    const float* b2   = (const float*)d_in[5];
    const float* eps  = (const float*)d_in[6];
    const int*   esrc = (const int*)d_in[7];
    const int*   edst = (const int*)d_in[8];
    float* out = (float*)d_out;

    char* ws = (char*)d_ws;
    size_t off = 0;
    auto alloc = [&](size_t bytes) { void* p = ws + off; off += (bytes + 511) & ~size_t(511); return p; };

    __bf16* W1T   = (__bf16*)alloc(128 * 256 * sizeof(__bf16));
    __bf16* W2T   = (__bf16*)alloc(128 * 256 * sizeof(__bf16));
    int* cnts     = (int*)  alloc((size_t)(SUP + NBK) * sizeof(int));       // supercnt | bktcnt
    int2* psup    = (int2*) alloc((size_t)SUP * CAPA * sizeof(int2));       // 14.5 MB
    int2* pairs2  = (int2*) alloc((size_t)NBK * CAPB * sizeof(int2));       // 19.2 MB
    unsigned* xb  = (unsigned*)alloc((size_t)NN * 64 * sizeof(unsigned));   // bf16 x
    unsigned* AXb = (unsigned*)alloc((size_t)NN * 64 * sizeof(unsigned));   // bf16 AX
    bool csr_ok = (off <= ws_size);

    if (csr_ok) {
        int* supercnt = cnts;
        int* bktcnt   = cnts + SUP;
        hipMemsetAsync(cnts, 0, (size_t)(SUP + NBK) * sizeof(int), stream);
        front_kernel<<<NBA, 512, 0, stream>>>(W1, W2, W1T, W2T, (const float4*)x,
                                              (uint2*)xb, esrc, edst, ev, supercnt, psup);
        refine_kernel<<<SUP * NSLC, 512, 0, stream>>>(psup, supercnt, bktcnt, pairs2);
        sort_gather_kernel<<<NBK, 512, 0, stream>>>(xb, bktcnt, pairs2, eps, (uint2*)AXb);
        int nblk = (NN + 63) / 64;
        mlp_kernel<__bf16><<<nblk, 256, 0, stream>>>((const __bf16*)AXb, W1T, W2T, b1, b2, out);
    } else {
        // fallback: atomic scatter path (fp32 AX in d_out)
        __bf16* W1Tf = (__bf16*)ws;
        __bf16* W2Tf = W1Tf + 128 * 256;
        convert_w_kernel<<<128, 256, 0, stream>>>(W1, W2, W1Tf, W2Tf);
        int n4 = NN * 128 / 4;
        init_ax_kernel<<<(n4 + 255) / 256, 256, 0, stream>>>((const float4*)x, (float4*)out, eps, n4);
        scatter_kernel<<<(NE * 64u) / 256u, 256, 0, stream>>>((const float2*)x, ev, esrc, edst, out);
        int nblk = (NN + 63) / 64;
        mlp_kernel<float><<<nblk, 256, 0, stream>>>(out, W1Tf, W2Tf, b1, b2, out);
    }
}